// Round 1
// baseline (210.858 us; speedup 1.0000x reference)
//
#include <hip/hip_runtime.h>

#define BB 4
#define SS 2048
#define DD 16
#define KK 204      // max(1, int(2048*0.1))
#define H1 64
#define H2 32

// ---------------- Kernel A: scores + q_part ----------------
__global__ void __launch_bounds__(256) score_q_kernel(
    const float* __restrict__ full, const float* __restrict__ sw1,
    const float* __restrict__ sb1, const float* __restrict__ sw2,
    const float* __restrict__ sb2, const float* __restrict__ mw1,
    float* __restrict__ scores, float* __restrict__ qpart) {
  int idx = blockIdx.x * blockDim.x + threadIdx.x;  // b*SS + s
  if (idx >= BB * SS) return;
  float x[16];
  const float* xp = full + idx * DD;
#pragma unroll
  for (int i = 0; i < 16; i++) x[i] = xp[i];

  float sc = sb2[0];
#pragma unroll
  for (int n = 0; n < 32; n++) {
    float a = sb1[n];
#pragma unroll
    for (int k = 0; k < 16; k++) a += x[k] * sw1[k * 32 + n];
    a = fmaxf(a, 0.f);
    sc += a * sw2[n];
  }
  scores[idx] = sc;

#pragma unroll
  for (int n = 0; n < 64; n++) {
    float a = 0.f;
#pragma unroll
    for (int k = 0; k < 16; k++) a += x[k] * mw1[k * 64 + n];  // w_q = mw1[:16]
    qpart[idx * 64 + n] = a;
  }
}

// ---------------- Kernel B: per-batch top-204 via bitonic sort ----------------
// key = (~monotone(f) << 32) | index  -> ascending sort = desc value, asc index
__global__ void __launch_bounds__(1024) topk_kernel(
    const float* __restrict__ scores, int* __restrict__ topidx) {
  __shared__ unsigned long long keys[SS];  // 16 KiB
  int b = blockIdx.x;
  int t = threadIdx.x;
  for (int i = t; i < SS; i += 1024) {
    float f = scores[b * SS + i];
    unsigned u = __float_as_uint(f);
    u = (u & 0x80000000u) ? ~u : (u | 0x80000000u);  // order-preserving asc
    u = ~u;                                          // descending by value
    keys[i] = ((unsigned long long)u << 32) | (unsigned)i;
  }
  __syncthreads();
  for (int k = 2; k <= SS; k <<= 1) {
    for (int j = k >> 1; j > 0; j >>= 1) {
      for (int i = t; i < SS; i += 1024) {
        int l = i ^ j;
        if (l > i) {
          unsigned long long a = keys[i], c = keys[l];
          bool asc = ((i & k) == 0);
          bool sw = asc ? (a > c) : (a < c);
          if (sw) { keys[i] = c; keys[l] = a; }
        }
      }
      __syncthreads();
    }
  }
  if (t < KK) topidx[b * KK + t] = (int)(keys[t] & 0xFFFFFFFFu);
}

// ---------------- Kernel C: kvb[b][j][n] = sel @ (wk+wv) + mb1 ----------------
__global__ void __launch_bounds__(64) kvb_kernel(
    const float* __restrict__ full, const int* __restrict__ topidx,
    const float* __restrict__ mw1, const float* __restrict__ mb1,
    float* __restrict__ kvb) {
  int bj = blockIdx.x;  // 816
  int b = bj / KK, j = bj % KK;
  int n = threadIdx.x;  // 0..63
  __shared__ float x[16];
  int sidx = topidx[b * KK + j];
  if (n < 16) x[n] = full[(b * SS + sidx) * DD + n];
  __syncthreads();
  float a = mb1[n];
#pragma unroll
  for (int k = 0; k < 16; k++)
    a += x[k] * (mw1[(16 + k) * 64 + n] + mw1[(32 + k) * 64 + n]);
  kvb[(b * KK + j) * 64 + n] = a;
}

// ---------------- Kernel D: main ----------------
// One block per (b,s). Threads = (jslot 0..7) x (n 0..31).
__global__ void __launch_bounds__(256) main_kernel(
    const float* __restrict__ qpart, const float* __restrict__ kvb,
    const float* __restrict__ mw2, const float* __restrict__ mb2,
    const float* __restrict__ mw3, const float* __restrict__ mb3,
    float* __restrict__ out) {
  int bs = blockIdx.x;       // 0..8191
  int b = bs >> 11;          // /2048
  int t = threadIdx.x;
  int jslot = t >> 5;        // 0..7
  int n = t & 31;

  __shared__ float h1s[8][64];
  __shared__ float qs[64];
  __shared__ float red[8][32];

  if (t < 64) qs[t] = qpart[bs * 64 + t];

  float wcol[64];
#pragma unroll
  for (int k = 0; k < 64; k++) wcol[k] = mw2[k * 32 + n];
  float bias2 = mb2[n];

  float acc = 0.f;
  const float* kvbb = kvb + b * KK * 64;

  for (int c = 0; c < 26; c++) {
    __syncthreads();  // protects h1s (and qs on first iter)
    // phase A: build h1 chunk (8 j x 64 k), 2 elems/thread
#pragma unroll
    for (int e = 0; e < 2; e++) {
      int idx2 = t * 2 + e;
      int jl = idx2 >> 6;    // 0..7
      int k = idx2 & 63;
      int j = c * 8 + jl;
      float v = 0.f;
      if (j < KK) v = fmaxf(qs[k] + kvbb[j * 64 + k], 0.f);
      h1s[jl][k] = v;
    }
    __syncthreads();
    // phase B: h2 = relu(h1 @ mw2 + mb2), accumulate over j
    int j = c * 8 + jslot;
    if (j < KK) {
      float s = bias2;
#pragma unroll
      for (int k = 0; k < 64; k++) s += h1s[jslot][k] * wcol[k];
      acc += fmaxf(s, 0.f);
    }
  }

  red[jslot][n] = acc;
  __syncthreads();
  if (t < 32) {
    float s = 0.f;
#pragma unroll
    for (int r = 0; r < 8; r++) s += red[r][t];
    red[0][t] = s * (1.0f / (float)KK);
  }
  __syncthreads();
  if (t < 16) {
    float o = mb3[t];
#pragma unroll
    for (int nn = 0; nn < 32; nn++) o += red[0][nn] * mw3[nn * 16 + t];
    out[bs * 16 + t] = o;
  }
}

extern "C" void kernel_launch(void* const* d_in, const int* in_sizes, int n_in,
                              void* d_out, int out_size, void* d_ws, size_t ws_size,
                              hipStream_t stream) {
  const float* full = (const float*)d_in[0];
  const float* sw1  = (const float*)d_in[1];
  const float* sb1  = (const float*)d_in[2];
  const float* sw2  = (const float*)d_in[3];
  const float* sb2  = (const float*)d_in[4];
  const float* mw1  = (const float*)d_in[5];
  const float* mb1  = (const float*)d_in[6];
  const float* mw2  = (const float*)d_in[7];
  const float* mb2  = (const float*)d_in[8];
  const float* mw3  = (const float*)d_in[9];
  const float* mb3  = (const float*)d_in[10];
  float* out = (float*)d_out;

  // workspace layout (floats)
  float* ws = (float*)d_ws;
  float* scores = ws;                        // 8192
  float* qpart  = scores + BB * SS;          // 524288
  float* kvb    = qpart + BB * SS * 64;      // 52224
  int*   topidx = (int*)(kvb + BB * KK * 64);// 816 ints

  score_q_kernel<<<(BB * SS) / 256, 256, 0, stream>>>(full, sw1, sb1, sw2, sb2,
                                                      mw1, scores, qpart);
  topk_kernel<<<BB, 1024, 0, stream>>>(scores, topidx);
  kvb_kernel<<<BB * KK, 64, 0, stream>>>(full, topidx, mw1, mb1, kvb);
  main_kernel<<<BB * SS, 256, 0, stream>>>(qpart, kvb, mw2, mb2, mw3, mb3, out);
}

// Round 2
// 67.119 us; speedup vs baseline: 3.1416x; 3.1416x over previous
//
#include <hip/hip_runtime.h>
#include <hip/hip_bf16.h>

#define BB 4
#define SS 2048
#define DD 16
#define KK 204      // max(1, int(2048*0.1))
#define JSPLIT 8

typedef __attribute__((ext_vector_type(8))) short short8;
typedef __attribute__((ext_vector_type(4))) float f32x4;

__device__ inline short f2bf(float x) {
  __hip_bfloat16 b = __float2bfloat16(x);
  return *reinterpret_cast<short*>(&b);
}

// ---------------- Kernel A: scores + q_part ----------------
__global__ void __launch_bounds__(256) score_q_kernel(
    const float* __restrict__ full, const float* __restrict__ sw1,
    const float* __restrict__ sb1, const float* __restrict__ sw2,
    const float* __restrict__ sb2, const float* __restrict__ mw1,
    float* __restrict__ scores, float* __restrict__ qpart) {
  int idx = blockIdx.x * blockDim.x + threadIdx.x;  // b*SS + s
  if (idx >= BB * SS) return;
  float x[16];
  const float* xp = full + idx * DD;
#pragma unroll
  for (int i = 0; i < 16; i++) x[i] = xp[i];

  float sc = sb2[0];
#pragma unroll
  for (int n = 0; n < 32; n++) {
    float a = sb1[n];
#pragma unroll
    for (int k = 0; k < 16; k++) a += x[k] * sw1[k * 32 + n];
    a = fmaxf(a, 0.f);
    sc += a * sw2[n];
  }
  scores[idx] = sc;

#pragma unroll
  for (int n = 0; n < 64; n++) {
    float a = 0.f;
#pragma unroll
    for (int k = 0; k < 16; k++) a += x[k] * mw1[k * 64 + n];  // w_q = mw1[:16]
    qpart[idx * 64 + n] = a;
  }
}

// ---------------- Kernel B: per-batch top-204 via bitonic sort ----------------
__global__ void __launch_bounds__(1024) topk_kernel(
    const float* __restrict__ scores, int* __restrict__ topidx) {
  __shared__ unsigned long long keys[SS];  // 16 KiB
  int b = blockIdx.x;
  int t = threadIdx.x;
  for (int i = t; i < SS; i += 1024) {
    float f = scores[b * SS + i];
    unsigned u = __float_as_uint(f);
    u = (u & 0x80000000u) ? ~u : (u | 0x80000000u);  // order-preserving asc
    u = ~u;                                          // descending by value
    keys[i] = ((unsigned long long)u << 32) | (unsigned)i;
  }
  __syncthreads();
  for (int k = 2; k <= SS; k <<= 1) {
    for (int j = k >> 1; j > 0; j >>= 1) {
      for (int i = t; i < SS; i += 1024) {
        int l = i ^ j;
        if (l > i) {
          unsigned long long a = keys[i], c = keys[l];
          bool asc = ((i & k) == 0);
          bool sw = asc ? (a > c) : (a < c);
          if (sw) { keys[i] = c; keys[l] = a; }
        }
      }
      __syncthreads();
    }
  }
  if (t < KK) topidx[b * KK + t] = (int)(keys[t] & 0xFFFFFFFFu);
}

// ---------------- Kernel C: kvb[b][j][n] = sel @ (wk+wv) + mb1 ----------------
__global__ void __launch_bounds__(64) kvb_kernel(
    const float* __restrict__ full, const int* __restrict__ topidx,
    const float* __restrict__ mw1, const float* __restrict__ mb1,
    float* __restrict__ kvb) {
  int bj = blockIdx.x;  // 816
  int b = bj / KK, j = bj % KK;
  int n = threadIdx.x;  // 0..63
  __shared__ float x[16];
  int sidx = topidx[b * KK + j];
  if (n < 16) x[n] = full[(b * SS + sidx) * DD + n];
  __syncthreads();
  float a = mb1[n];
#pragma unroll
  for (int k = 0; k < 16; k++)
    a += x[k] * (mw1[(16 + k) * 64 + n] + mw1[(32 + k) * 64 + n]);
  kvb[(b * KK + j) * 64 + n] = a;
}

// ---------------- Kernel D: main (MFMA bf16) ----------------
// Block = 8 waves, one m-tile of 16 (b,s) rows; wave w handles j in [w*26, ...).
// A frag layout (16x16x32 bf16): lane l holds A[m=l&15][k=8*(l>>4)+i], i=0..7.
// B frag:                        lane l holds B[k=8*(l>>4)+i][n=l&15].
// D frag (m89-verified):         lane l, reg r -> D[m=4*(l>>4)+r][n=l&15].
__global__ void __launch_bounds__(512) main_mfma_kernel(
    const float* __restrict__ qpart, const float* __restrict__ kvb,
    const float* __restrict__ mw2, const float* __restrict__ mb2,
    const float* __restrict__ mw3, const float* __restrict__ mb3,
    float* __restrict__ out) {
  int mtile = blockIdx.x;            // 0..511
  int bs_base = mtile * 16;
  int b = bs_base >> 11;
  int t = threadIdx.x;
  int w = t >> 6;
  int l = t & 63;
  int ml = l & 15;
  int g = l >> 4;

  // q in registers: qv[kh][half] covers k = kh*32 + 8g + (half*4 .. half*4+3)
  f32x4 qv[2][2];
  {
    const float* qp = qpart + (bs_base + ml) * 64 + 8 * g;
    qv[0][0] = *(const f32x4*)(qp);
    qv[0][1] = *(const f32x4*)(qp + 4);
    qv[1][0] = *(const f32x4*)(qp + 32);
    qv[1][1] = *(const f32x4*)(qp + 36);
  }

  // B fragments of mw2 (64x32), held in registers for the whole kernel
  short8 bfrag[2][2];  // [ntile][khalf]
#pragma unroll
  for (int nt = 0; nt < 2; nt++)
#pragma unroll
    for (int kh = 0; kh < 2; kh++)
#pragma unroll
      for (int i = 0; i < 8; i++) {
        int k = kh * 32 + 8 * g + i;
        bfrag[nt][kh][i] = f2bf(mw2[k * 32 + nt * 16 + ml]);
      }

  // bias splat fragment (mb2), used as C-in of first MFMA each j
  f32x4 biasfrag[2];
#pragma unroll
  for (int nt = 0; nt < 2; nt++) {
    float bv = mb2[nt * 16 + ml];
    f32x4 bf;
    bf[0] = bv; bf[1] = bv; bf[2] = bv; bf[3] = bv;
    biasfrag[nt] = bf;
  }

  float accs[2][4] = {};
  int jbeg = w * 26;
  int jend = jbeg + 26;
  if (jend > KK) jend = KK;
  const float* kvbb = kvb + b * KK * 64 + 8 * g;

#pragma unroll 2
  for (int j = jbeg; j < jend; j++) {
    const float* kp = kvbb + j * 64;
    f32x4 kv[2][2];
    kv[0][0] = *(const f32x4*)(kp);
    kv[0][1] = *(const f32x4*)(kp + 4);
    kv[1][0] = *(const f32x4*)(kp + 32);
    kv[1][1] = *(const f32x4*)(kp + 36);

    short8 afrag[2];
#pragma unroll
    for (int kh = 0; kh < 2; kh++)
#pragma unroll
      for (int hf = 0; hf < 2; hf++)
#pragma unroll
        for (int i = 0; i < 4; i++) {
          float h = fmaxf(qv[kh][hf][i] + kv[kh][hf][i], 0.f);
          afrag[kh][hf * 4 + i] = f2bf(h);
        }

#pragma unroll
    for (int nt = 0; nt < 2; nt++) {
      f32x4 c = __builtin_amdgcn_mfma_f32_16x16x32_bf16(
          afrag[0], bfrag[nt][0], biasfrag[nt], 0, 0, 0);
      c = __builtin_amdgcn_mfma_f32_16x16x32_bf16(
          afrag[1], bfrag[nt][1], c, 0, 0, 0);
#pragma unroll
      for (int r = 0; r < 4; r++) accs[nt][r] += fmaxf(c[r], 0.f);
    }
  }

  // cross-wave reduction over j-splits
  __shared__ float red[JSPLIT][512];
#pragma unroll
  for (int nt = 0; nt < 2; nt++)
#pragma unroll
    for (int r = 0; r < 4; r++)
      red[w][(4 * g + r) * 32 + nt * 16 + ml] = accs[nt][r];
  __syncthreads();
  float sum = 0.f;
#pragma unroll
  for (int ww = 0; ww < JSPLIT; ww++) sum += red[ww][t];
  sum *= (1.0f / (float)KK);
  red[0][t] = sum;   // each thread touches only its own column
  __syncthreads();

  if (t < 256) {
    int m = t >> 4, dc = t & 15;
    float o = mb3[dc];
#pragma unroll
    for (int n = 0; n < 32; n++) o += red[0][m * 32 + n] * mw3[n * 16 + dc];
    out[(bs_base + m) * 16 + dc] = o;
  }
}

extern "C" void kernel_launch(void* const* d_in, const int* in_sizes, int n_in,
                              void* d_out, int out_size, void* d_ws, size_t ws_size,
                              hipStream_t stream) {
  const float* full = (const float*)d_in[0];
  const float* sw1  = (const float*)d_in[1];
  const float* sb1  = (const float*)d_in[2];
  const float* sw2  = (const float*)d_in[3];
  const float* sb2  = (const float*)d_in[4];
  const float* mw1  = (const float*)d_in[5];
  const float* mb1  = (const float*)d_in[6];
  const float* mw2  = (const float*)d_in[7];
  const float* mb2  = (const float*)d_in[8];
  const float* mw3  = (const float*)d_in[9];
  const float* mb3  = (const float*)d_in[10];
  float* out = (float*)d_out;

  // workspace layout (floats)
  float* ws = (float*)d_ws;
  float* scores = ws;                        // 8192
  float* qpart  = scores + BB * SS;          // 524288
  float* kvb    = qpart + BB * SS * 64;      // 52224
  int*   topidx = (int*)(kvb + BB * KK * 64);// 816 ints

  score_q_kernel<<<(BB * SS) / 256, 256, 0, stream>>>(full, sw1, sb1, sw2, sb2,
                                                      mw1, scores, qpart);
  topk_kernel<<<BB, 1024, 0, stream>>>(scores, topidx);
  kvb_kernel<<<BB * KK, 64, 0, stream>>>(full, topidx, mw1, mb1, kvb);
  main_mfma_kernel<<<BB * SS / 16, 512, 0, stream>>>(qpart, kvb, mw2, mb2, mw3,
                                                     mb3, out);
}

// Round 3
// 45.188 us; speedup vs baseline: 4.6662x; 1.4853x over previous
//
#include <hip/hip_runtime.h>
#include <hip/hip_bf16.h>

#define BB 4
#define SS 2048
#define DD 16
#define KK 204      // max(1, int(2048*0.1))
#define JSPLIT 8

typedef __attribute__((ext_vector_type(8))) short short8;
typedef __attribute__((ext_vector_type(4))) float f32x4;

__device__ inline short f2bf(float x) {
  __hip_bfloat16 b = __float2bfloat16(x);
  return *reinterpret_cast<short*>(&b);
}

// ---------------- Kernel A: scores + q_part ----------------
__global__ void __launch_bounds__(256) score_q_kernel(
    const float* __restrict__ full, const float* __restrict__ sw1,
    const float* __restrict__ sb1, const float* __restrict__ sw2,
    const float* __restrict__ sb2, const float* __restrict__ mw1,
    float* __restrict__ scores, float* __restrict__ qpart) {
  int idx = blockIdx.x * blockDim.x + threadIdx.x;  // b*SS + s
  if (idx >= BB * SS) return;
  float x[16];
  const float* xp = full + idx * DD;
#pragma unroll
  for (int i = 0; i < 16; i++) x[i] = xp[i];

  float sc = sb2[0];
#pragma unroll
  for (int n = 0; n < 32; n++) {
    float a = sb1[n];
#pragma unroll
    for (int k = 0; k < 16; k++) a += x[k] * sw1[k * 32 + n];
    a = fmaxf(a, 0.f);
    sc += a * sw2[n];
  }
  scores[idx] = sc;

#pragma unroll
  for (int n = 0; n < 64; n++) {
    float a = 0.f;
#pragma unroll
    for (int k = 0; k < 16; k++) a += x[k] * mw1[k * 64 + n];  // w_q = mw1[:16]
    qpart[idx * 64 + n] = a;
  }
}

// ---------------- Kernel B: per-batch top-204 via radix select ----------------
// key = monotone(score)<<11 | (2047-i): larger key = larger value, then smaller
// index. Keys are unique, so "key >= K*" (K* = rank-204 key) selects exactly
// 204 items. Output topidx is UNORDERED — downstream mean over j is
// order-invariant, so only the set matters.
__global__ void __launch_bounds__(256) topk_select_kernel(
    const float* __restrict__ scores, int* __restrict__ topidx) {
  int b = blockIdx.x;
  int t = threadIdx.x;

  unsigned long long key[8];
#pragma unroll
  for (int e = 0; e < 8; e++) {
    int i = t + e * 256;
    float f = scores[b * SS + i];
    unsigned u = __float_as_uint(f);
    u = (u & 0x80000000u) ? ~u : (u | 0x80000000u);  // order-preserving asc
    key[e] = ((unsigned long long)u << 11) | (unsigned)(SS - 1 - i);
  }

  __shared__ int hist[256];
  __shared__ int sufs[256];
  __shared__ unsigned long long s_prefix;
  __shared__ int s_r;
  __shared__ int s_cnt;
  if (t == 0) { s_prefix = 0ull; s_r = KK; s_cnt = 0; }

  for (int s = 40; s >= 0; s -= 8) {
    hist[t] = 0;
    __syncthreads();                 // also publishes s_prefix/s_r updates
    unsigned long long pfx = s_prefix;
#pragma unroll
    for (int e = 0; e < 8; e++) {
      if ((key[e] >> (s + 8)) == pfx)
        atomicAdd(&hist[(int)((key[e] >> s) & 0xFF)], 1);
    }
    __syncthreads();
    // suffix sum: sufs[t] = sum_{d >= t} hist[d]
    sufs[t] = hist[t];
    __syncthreads();
    for (int off = 1; off < 256; off <<= 1) {
      int add = (t + off < 256) ? sufs[t + off] : 0;
      __syncthreads();
      sufs[t] += add;
      __syncthreads();
    }
    int r = s_r;
    int nxt = (t < 255) ? sufs[t + 1] : 0;
    if (sufs[t] >= r && nxt < r) {   // exactly one thread matches
      s_prefix = (pfx << 8) | (unsigned)t;
      s_r = r - nxt;
    }
    __syncthreads();
  }

  unsigned long long kstar = s_prefix;
#pragma unroll
  for (int e = 0; e < 8; e++) {
    if (key[e] >= kstar) {
      int pos = atomicAdd(&s_cnt, 1);
      topidx[b * KK + pos] = t + e * 256;
    }
  }
}

// ---------------- Kernel C: kvb[b][j][n] = sel @ (wk+wv) + mb1 ----------------
__global__ void __launch_bounds__(64) kvb_kernel(
    const float* __restrict__ full, const int* __restrict__ topidx,
    const float* __restrict__ mw1, const float* __restrict__ mb1,
    float* __restrict__ kvb) {
  int bj = blockIdx.x;  // 816
  int b = bj / KK, j = bj % KK;
  int n = threadIdx.x;  // 0..63
  __shared__ float x[16];
  int sidx = topidx[b * KK + j];
  if (n < 16) x[n] = full[(b * SS + sidx) * DD + n];
  __syncthreads();
  float a = mb1[n];
#pragma unroll
  for (int k = 0; k < 16; k++)
    a += x[k] * (mw1[(16 + k) * 64 + n] + mw1[(32 + k) * 64 + n]);
  kvb[(b * KK + j) * 64 + n] = a;
}

// ---------------- Kernel D: main (MFMA bf16) ----------------
// Block = 8 waves, one m-tile of 16 (b,s) rows; wave w handles 26 j's.
// A frag (16x16x32 bf16): lane l holds A[m=l&15][k=8*(l>>4)+i], i=0..7.
// B frag:                 lane l holds B[k=8*(l>>4)+i][n=l&15].
// D frag (m89-verified):  lane l, reg r -> D[m=4*(l>>4)+r][n=l&15].
__global__ void __launch_bounds__(512) main_mfma_kernel(
    const float* __restrict__ qpart, const float* __restrict__ kvb,
    const float* __restrict__ mw2, const float* __restrict__ mb2,
    const float* __restrict__ mw3, const float* __restrict__ mb3,
    float* __restrict__ out) {
  int mtile = blockIdx.x;            // 0..511
  int bs_base = mtile * 16;
  int b = bs_base >> 11;
  int t = threadIdx.x;
  int w = t >> 6;
  int l = t & 63;
  int ml = l & 15;
  int g = l >> 4;

  f32x4 qv[2][2];
  {
    const float* qp = qpart + (bs_base + ml) * 64 + 8 * g;
    qv[0][0] = *(const f32x4*)(qp);
    qv[0][1] = *(const f32x4*)(qp + 4);
    qv[1][0] = *(const f32x4*)(qp + 32);
    qv[1][1] = *(const f32x4*)(qp + 36);
  }

  short8 bfrag[2][2];  // [ntile][khalf]
#pragma unroll
  for (int nt = 0; nt < 2; nt++)
#pragma unroll
    for (int kh = 0; kh < 2; kh++)
#pragma unroll
      for (int i = 0; i < 8; i++) {
        int k = kh * 32 + 8 * g + i;
        bfrag[nt][kh][i] = f2bf(mw2[k * 32 + nt * 16 + ml]);
      }

  f32x4 biasfrag[2];
#pragma unroll
  for (int nt = 0; nt < 2; nt++) {
    float bv = mb2[nt * 16 + ml];
    f32x4 bf;
    bf[0] = bv; bf[1] = bv; bf[2] = bv; bf[3] = bv;
    biasfrag[nt] = bf;
  }

  float accs[2][4] = {};
  int jbeg = w * 26;
  int jend = jbeg + 26;
  if (jend > KK) jend = KK;
  const float* kvbb = kvb + b * KK * 64 + 8 * g;

#pragma unroll 2
  for (int j = jbeg; j < jend; j++) {
    const float* kp = kvbb + j * 64;
    f32x4 kv[2][2];
    kv[0][0] = *(const f32x4*)(kp);
    kv[0][1] = *(const f32x4*)(kp + 4);
    kv[1][0] = *(const f32x4*)(kp + 32);
    kv[1][1] = *(const f32x4*)(kp + 36);

    short8 afrag[2];
#pragma unroll
    for (int kh = 0; kh < 2; kh++)
#pragma unroll
      for (int hf = 0; hf < 2; hf++)
#pragma unroll
        for (int i = 0; i < 4; i++) {
          float h = fmaxf(qv[kh][hf][i] + kv[kh][hf][i], 0.f);
          afrag[kh][hf * 4 + i] = f2bf(h);
        }

#pragma unroll
    for (int nt = 0; nt < 2; nt++) {
      f32x4 c = __builtin_amdgcn_mfma_f32_16x16x32_bf16(
          afrag[0], bfrag[nt][0], biasfrag[nt], 0, 0, 0);
      c = __builtin_amdgcn_mfma_f32_16x16x32_bf16(
          afrag[1], bfrag[nt][1], c, 0, 0, 0);
#pragma unroll
      for (int r = 0; r < 4; r++) accs[nt][r] += fmaxf(c[r], 0.f);
    }
  }

  __shared__ float red[JSPLIT][512];
#pragma unroll
  for (int nt = 0; nt < 2; nt++)
#pragma unroll
    for (int r = 0; r < 4; r++)
      red[w][(4 * g + r) * 32 + nt * 16 + ml] = accs[nt][r];
  __syncthreads();
  float sum = 0.f;
#pragma unroll
  for (int ww = 0; ww < JSPLIT; ww++) sum += red[ww][t];
  sum *= (1.0f / (float)KK);
  red[0][t] = sum;
  __syncthreads();

  if (t < 256) {
    int m = t >> 4, dc = t & 15;
    float o = mb3[dc];
#pragma unroll
    for (int n = 0; n < 32; n++) o += red[0][m * 32 + n] * mw3[n * 16 + dc];
    out[(bs_base + m) * 16 + dc] = o;
  }
}

extern "C" void kernel_launch(void* const* d_in, const int* in_sizes, int n_in,
                              void* d_out, int out_size, void* d_ws, size_t ws_size,
                              hipStream_t stream) {
  const float* full = (const float*)d_in[0];
  const float* sw1  = (const float*)d_in[1];
  const float* sb1  = (const float*)d_in[2];
  const float* sw2  = (const float*)d_in[3];
  const float* sb2  = (const float*)d_in[4];
  const float* mw1  = (const float*)d_in[5];
  const float* mb1  = (const float*)d_in[6];
  const float* mw2  = (const float*)d_in[7];
  const float* mb2  = (const float*)d_in[8];
  const float* mw3  = (const float*)d_in[9];
  const float* mb3  = (const float*)d_in[10];
  float* out = (float*)d_out;

  float* ws = (float*)d_ws;
  float* scores = ws;                        // 8192
  float* qpart  = scores + BB * SS;          // 524288
  float* kvb    = qpart + BB * SS * 64;      // 52224
  int*   topidx = (int*)(kvb + BB * KK * 64);// 816 ints

  score_q_kernel<<<(BB * SS) / 256, 256, 0, stream>>>(full, sw1, sb1, sw2, sb2,
                                                      mw1, scores, qpart);
  topk_select_kernel<<<BB, 256, 0, stream>>>(scores, topidx);
  kvb_kernel<<<BB * KK, 64, 0, stream>>>(full, topidx, mw1, mb1, kvb);
  main_mfma_kernel<<<BB * SS / 16, 512, 0, stream>>>(qpart, kvb, mw2, mb2, mw3,
                                                     mb3, out);
}